// Round 2
// 1198.208 us; speedup vs baseline: 1.2920x; 1.2920x over previous
//
#include <hip/hip_runtime.h>

// Problem constants
constexpr int Bc = 32, Sc = 512, Dc = 768, Mc = 32, Tc = 30;
constexpr int Hc = 12, DFFc = 3072, Lc = 4, Ec = 100000, HDc = 64;
constexpr int TOK = Bc * Mc; // 1024 token rows
constexpr int KC2 = 112;     // padded K for classifier GEMMs (16B-aligned bf16 rows)

typedef float floatx4 __attribute__((ext_vector_type(4)));
typedef __bf16 bfrag8 __attribute__((ext_vector_type(8)));
typedef unsigned short usx8 __attribute__((ext_vector_type(8)));
typedef unsigned short usx4 __attribute__((ext_vector_type(4)));

__device__ __forceinline__ unsigned short f32_to_bf16(float f) {
    unsigned int u = __float_as_uint(f);
    unsigned int r = (u + 0x7FFFu + ((u >> 16) & 1u)) >> 16; // RNE
    return (unsigned short)r;
}

// ---------------------------------------------------------------- fused weight cvt
// 7 segments max; src==nullptr => zero-fill (used for cls_w1 pad rows)
struct CvtSegs {
    const float* src[7];
    unsigned short* dst[7];
    unsigned int end[7];   // cumulative counts in float4-chunks
    unsigned int total;
};

__global__ __launch_bounds__(256)
void cvt_multi_kernel(CvtSegs a) {
    const unsigned int stride = gridDim.x * 256;
    for (unsigned int i = blockIdx.x * 256 + threadIdx.x; i < a.total; i += stride) {
        int s = 0;
        while (i >= a.end[s]) ++s;
        const unsigned int off = i - (s ? a.end[s - 1] : 0u);
        usx4 o = (usx4)0;
        if (a.src[s]) {
            floatx4 v = *(const floatx4*)(a.src[s] + 4 * (size_t)off);
            #pragma unroll
            for (int j = 0; j < 4; ++j) o[j] = f32_to_bf16(v[j]);
        }
        *(usx4*)(a.dst[s] + 4 * (size_t)off) = o;
    }
}

// cls_w2 [E,100] f32 -> [E,112] bf16 (12 zero pad cols), aligned rows
__global__ __launch_bounds__(256)
void cvt_c2_kernel(const float* __restrict__ src, unsigned short* __restrict__ dst) {
    const int total = Ec * (KC2 / 8);          // 14 chunks of 8 per row
    const int stride = gridDim.x * 256;
    for (int c = blockIdx.x * 256 + threadIdx.x; c < total; c += stride) {
        const int row = c / 14, j = c - 14 * (c / 14);
        const int col0 = j * 8;
        const float* sp = src + (size_t)row * 100 + col0;
        usx8 o = (usx8)0;
        if (col0 + 8 <= 100) {
            floatx4 v0 = *(const floatx4*)(sp);
            floatx4 v1 = *(const floatx4*)(sp + 4);
            #pragma unroll
            for (int jj = 0; jj < 4; ++jj) { o[jj] = f32_to_bf16(v0[jj]); o[4 + jj] = f32_to_bf16(v1[jj]); }
        } else {
            #pragma unroll
            for (int jj = 0; jj < 8; ++jj)
                if (col0 + jj < 100) o[jj] = f32_to_bf16(sp[jj]);
        }
        *(usx8*)(dst + (size_t)row * KC2 + col0) = o;
    }
}

// ---------------------------------------------------------------- mention pool
__global__ __launch_bounds__(256)
void pool_kernel(const float* __restrict__ lhs, const float* __restrict__ attn_w,
                 const int* __restrict__ pos, const int* __restrict__ emask,
                 float* __restrict__ x0, unsigned short* __restrict__ x0b) {
    const int bm = blockIdx.x;          // b*32+m
    const int b = bm >> 5;
    const int tid = threadIdx.x;
    __shared__ float s_logit[32];
    __shared__ float s_w[32];
    __shared__ int s_valid[32];

    if (tid == 0) {
        int em = emask[bm];
        int ok = 1;
        for (int t = 0; t < Tc; ++t) {
            if (pos[bm * Tc + t] == -1) ok = 0;
            s_valid[t] = (ok && em) ? 1 : 0;
        }
    }
    __syncthreads();

    const int wid = tid >> 6, lane = tid & 63;
    for (int t = wid; t < Tc; t += 4) {
        float p = 0.f;
        const float* row = lhs + ((size_t)b * Sc + t) * Dc;
        for (int d = lane; d < Dc; d += 64) p += row[d] * attn_w[d];
        #pragma unroll
        for (int off = 32; off > 0; off >>= 1) p += __shfl_down(p, off);
        if (lane == 0) s_logit[t] = s_valid[t] ? p : 0.0f;  // attn_b cancels in softmax
    }
    __syncthreads();
    if (tid == 0) {
        float mx = -1e30f;
        for (int t = 0; t < Tc; ++t) mx = fmaxf(mx, s_logit[t]);
        float sum = 0.f;
        for (int t = 0; t < Tc; ++t) { float e = expf(s_logit[t] - mx); s_w[t] = e; sum += e; }
        float inv = 1.0f / sum;
        for (int t = 0; t < Tc; ++t) s_w[t] = s_valid[t] ? s_w[t] * inv : 0.0f;
    }
    __syncthreads();
    for (int d = tid; d < Dc; d += 256) {
        float acc = 0.f;
        for (int t = 0; t < Tc; ++t) acc += s_w[t] * lhs[((size_t)b * Sc + t) * Dc + d];
        x0[(size_t)bm * Dc + d] = acc;
        x0b[(size_t)bm * Dc + d] = f32_to_bf16(acc);
    }
}

// ---------------------------------------------------------------- GEMM  C = A @ B^T (+bias) (opt relu)
// A: bf16 [M,lda]; B: bf16 [N,ldb]; C: f32 or bf16 [M,ldc]. M multiple of BM.
// Split-K via blockIdx.z: A,B advance z*K columns; C advances z*M*ldc (partial slabs).
// nxReal>0 enables XCD chunk swizzle (requires gridDim.x % 8 == 0); padded col-tiles exit.
template <int BM, int BN, int WM, int WN, int OUTBF>
__global__ __launch_bounds__(256)
void gemm_bf16_kernel(const unsigned short* __restrict__ A, int lda,
                      const unsigned short* __restrict__ B, int ldb,
                      const float* __restrict__ bias, void* __restrict__ Cv,
                      int ldc, int M, int N, int K, int relu, int nxReal) {
    constexpr int BK = 64;
    constexpr int LK = BK + 8;  // padded LDS row stride: 144 B -> 2-way bank alias (free)
    __shared__ unsigned short lA[BM * LK];
    __shared__ unsigned short lB[BN * LK];

    int bx, by;
    if (nxReal > 0) {
        // chunked bijection: XCD k (== bid%8 round-robin) owns contiguous col range,
        // iterating all row-tiles of a column consecutively -> B tile stays in that XCD's L2.
        const int gx = gridDim.x, gy = gridDim.y;
        const int lb = blockIdx.y * gx + blockIdx.x;
        const int xcd = lb & 7, p = lb >> 3;
        const int pq = p / gy;
        bx = xcd * (gx >> 3) + pq;
        by = p - pq * gy;
        if (bx >= nxReal) return;   // uniform across block, before any barrier
    } else {
        bx = blockIdx.x; by = blockIdx.y;
    }
    const int z = blockIdx.z;
    A += (size_t)z * K;
    B += (size_t)z * K;

    const int tid = threadIdx.x;
    const int bm0 = by * BM;
    const int bn0 = bx * BN;

    const int wid = tid >> 6;
    const int lane = tid & 63;
    const int quad = lane >> 4;
    const int l16 = lane & 15;
    const int wr = (wid >> 1) * (WM * 16);
    const int wc = (wid & 1) * (WN * 16);

    const int tr = tid >> 3;         // 0..31
    const int tk = (tid & 7) * 8;    // 0..56

    floatx4 acc[WM][WN] = {};

    for (int k0 = 0; k0 < K; k0 += BK) {
        const int gk0 = k0 + tk;
        // stage A (bf16 copy)
        for (int r = tr; r < BM; r += 32) {
            const unsigned short* ap = A + (size_t)(bm0 + r) * lda + gk0;
            usx8 t8 = (usx8)0;
            if (gk0 + 8 <= K) {
                t8 = *(const usx8*)ap;
            } else {
                #pragma unroll
                for (int j = 0; j < 8; ++j)
                    if (gk0 + j < K) t8[j] = ap[j];
            }
            *(usx8*)(&lA[r * LK + tk]) = t8;
        }
        // stage B (bf16 copy)
        for (int r = tr; r < BN; r += 32) {
            const int gn = bn0 + r;
            usx8 t8 = (usx8)0;
            if (gn < N) {
                const unsigned short* bp = B + (size_t)gn * ldb + gk0;
                if (gk0 + 8 <= K) {
                    t8 = *(const usx8*)bp;
                } else {
                    #pragma unroll
                    for (int j = 0; j < 8; ++j)
                        if (gk0 + j < K) t8[j] = bp[j];
                }
            }
            *(usx8*)(&lB[r * LK + tk]) = t8;
        }
        __syncthreads();
        #pragma unroll
        for (int kk = 0; kk < BK; kk += 32) {
            bfrag8 af[WM], bfr[WN];
            #pragma unroll
            for (int i = 0; i < WM; ++i)
                af[i] = *(const bfrag8*)(&lA[(wr + i * 16 + l16) * LK + kk + quad * 8]);
            #pragma unroll
            for (int j = 0; j < WN; ++j)
                bfr[j] = *(const bfrag8*)(&lB[(wc + j * 16 + l16) * LK + kk + quad * 8]);
            #pragma unroll
            for (int i = 0; i < WM; ++i)
                #pragma unroll
                for (int j = 0; j < WN; ++j)
                    acc[i][j] = __builtin_amdgcn_mfma_f32_16x16x32_bf16(af[i], bfr[j], acc[i][j], 0, 0, 0);
        }
        __syncthreads();
    }

    #pragma unroll
    for (int i = 0; i < WM; ++i) {
        #pragma unroll
        for (int j = 0; j < WN; ++j) {
            const int col = bn0 + wc + j * 16 + l16;
            if (col < N) {
                const int row0 = bm0 + wr + i * 16 + quad * 4;
                const float bv = bias ? bias[col] : 0.0f;
                #pragma unroll
                for (int r = 0; r < 4; ++r) {
                    float v = acc[i][j][r] + bv;
                    if (relu) v = fmaxf(v, 0.0f);
                    const size_t idx = (size_t)z * M * ldc + (size_t)(row0 + r) * ldc + col;
                    if (OUTBF) ((unsigned short*)Cv)[idx] = f32_to_bf16(v);
                    else       ((float*)Cv)[idx] = v;
                }
            }
        }
    }
}

// ---------------------------------------------------------------- attention (one block per (b,h))
__global__ __launch_bounds__(256)
void attn_kernel(const float* __restrict__ qkv, unsigned short* __restrict__ outb) {
    const int bh = blockIdx.x;
    const int b = bh / Hc, h = bh % Hc;
    const int tid = threadIdx.x;
    __shared__ float sQ[32][65];
    __shared__ float sK[32][65];
    __shared__ float sV[32][65];
    __shared__ float sS[32][33];

    const int m = tid >> 3;
    const int c0 = (tid & 7) * 8;
    {
        const size_t rbase = ((size_t)(b * 32 + m)) * (3 * Dc);
        #pragma unroll
        for (int j = 0; j < 8; ++j) {
            sQ[m][c0 + j] = qkv[rbase + h * HDc + c0 + j];
            sK[m][c0 + j] = qkv[rbase + Dc + h * HDc + c0 + j];
            sV[m][c0 + j] = qkv[rbase + 2 * Dc + h * HDc + c0 + j];
        }
    }
    __syncthreads();

    #pragma unroll
    for (int u = 0; u < 4; ++u) {
        const int e = tid * 4 + u;
        const int q = e >> 5, k = e & 31;
        float s = 0.f;
        #pragma unroll
        for (int d = 0; d < HDc; ++d) s += sQ[q][d] * sK[k][d];
        sS[q][k] = s * 0.125f;
    }
    __syncthreads();
    if (tid < 32) {
        float mx = -1e30f;
        for (int k = 0; k < 32; ++k) mx = fmaxf(mx, sS[tid][k]);
        float sum = 0.f;
        for (int k = 0; k < 32; ++k) { float e = expf(sS[tid][k] - mx); sS[tid][k] = e; sum += e; }
        const float inv = 1.0f / sum;
        for (int k = 0; k < 32; ++k) sS[tid][k] *= inv;
    }
    __syncthreads();
    float o[8] = {};
    for (int k = 0; k < 32; ++k) {
        const float p = sS[m][k];
        #pragma unroll
        for (int j = 0; j < 8; ++j) o[j] += p * sV[k][c0 + j];
    }
    usx8 o8;
    #pragma unroll
    for (int j = 0; j < 8; ++j) o8[j] = f32_to_bf16(o[j]);
    *(usx8*)(&outb[((size_t)(b * 32 + m)) * Dc + h * HDc + c0]) = o8;
}

// ---------------------------------------------------------------- residual + split-K sum + bias + layernorm
// out = LN(xa + sum_{s<nslab} xs[s] + badd) ; writes f32 and bf16 copies
__global__ __launch_bounds__(256)
void addln_kernel(const float* __restrict__ xa, const float* __restrict__ xs, int nslab,
                  const float* __restrict__ badd, const float* __restrict__ g,
                  const float* __restrict__ be, float* __restrict__ outf,
                  unsigned short* __restrict__ outb) {
    const int row = blockIdx.x;
    const int tid = threadIdx.x;
    __shared__ float red[8];
    float v[3];
    float s = 0.f, sq = 0.f;
    #pragma unroll
    for (int i = 0; i < 3; ++i) {
        const int d = tid + i * 256;
        float x = xa[(size_t)row * Dc + d] + badd[d];
        for (int sl = 0; sl < nslab; ++sl)
            x += xs[((size_t)sl * TOK + row) * Dc + d];
        v[i] = x; s += x; sq += x * x;
    }
    #pragma unroll
    for (int off = 32; off > 0; off >>= 1) {
        s += __shfl_down(s, off);
        sq += __shfl_down(sq, off);
    }
    if ((tid & 63) == 0) { red[tid >> 6] = s; red[4 + (tid >> 6)] = sq; }
    __syncthreads();
    const float ts = red[0] + red[1] + red[2] + red[3];
    const float tq = red[4] + red[5] + red[6] + red[7];
    const float mean = ts * (1.0f / Dc);
    const float var = tq * (1.0f / Dc) - mean * mean;
    const float inv = rsqrtf(var + 1e-5f);
    #pragma unroll
    for (int i = 0; i < 3; ++i) {
        const int d = tid + i * 256;
        const float y = (v[i] - mean) * inv * g[d] + be[d];
        outf[(size_t)row * Dc + d] = y;
        outb[(size_t)row * Dc + d] = f32_to_bf16(y);
    }
}

// ---------------------------------------------------------------- launch
extern "C" void kernel_launch(void* const* d_in, const int* in_sizes, int n_in,
                              void* d_out, int out_size, void* d_ws, size_t ws_size,
                              hipStream_t stream) {
    const float* lhs   = (const float*)d_in[0];
    const float* attnw = (const float*)d_in[1];
    // d_in[2] attn_b: scalar, cancels in softmax
    const float* ipw = (const float*)d_in[3];
    const float* ipb = (const float*)d_in[4];
    const float* oww = (const float*)d_in[5];
    const float* owb = (const float*)d_in[6];
    const float* g1  = (const float*)d_in[7];
    const float* b1  = (const float*)d_in[8];
    const float* l1w = (const float*)d_in[9];
    const float* l1b = (const float*)d_in[10];
    const float* l2w = (const float*)d_in[11];
    const float* l2b = (const float*)d_in[12];
    const float* g2  = (const float*)d_in[13];
    const float* b2  = (const float*)d_in[14];
    const float* cw1 = (const float*)d_in[15];
    const float* cw2 = (const float*)d_in[16];
    const float* cb2 = (const float*)d_in[17];
    const int* pos   = (const int*)d_in[18];
    const int* emask = (const int*)d_in[19];
    float* out = (float*)d_out;

    constexpr size_t N_IP = (size_t)Lc * 3 * Dc * Dc;   // 7,077,888
    constexpr size_t N_OW = (size_t)Lc * Dc * Dc;       // 2,359,296
    constexpr size_t N_L1 = (size_t)Lc * DFFc * Dc;     // 9,437,184
    constexpr size_t N_L2 = (size_t)Lc * Dc * DFFc;     // 9,437,184
    constexpr size_t N_C1 = (size_t)KC2 * Dc;           // 86,016 (112 rows, 12 zero)

    // ---- memory map ----
    // d_ws (only what the FINAL GEMM reads): bw_c2 [E,112] bf16 (22.4 MB) + bufCb (0.23 MB).
    // Everything else (dead before the final GEMM overwrites all of d_out) lives in the
    // TAIL of d_out (~96.1 MB of 409.6 MB): f32 activations first (16B aligned), then
    // bf16 weights + bf16 activations.
    char* ws = (char*)d_ws;
    unsigned short* bw_c2 = (unsigned short*)ws;                 // [E,112] bf16
    unsigned short* bufCb = bw_c2 + (size_t)Ec * KC2;            // [1024,112] bf16

    constexpr size_t F_XA   = (size_t)TOK * Dc;          // 786,432
    constexpr size_t F_QKV  = (size_t)TOK * 3 * Dc;      // 2,359,296
    constexpr size_t F_SLAB = (size_t)4 * TOK * Dc;      // 3,145,728
    constexpr size_t S_ACT  = (size_t)TOK * Dc;          // bf16 activation count
    constexpr size_t S_FFH  = (size_t)TOK * DFFc;
    constexpr size_t tail_bytes =
        4 * (F_XA + F_XA + F_QKV + F_SLAB) +
        2 * (N_IP + N_OW + N_L1 + N_L2 + N_C1 + 3 * S_ACT + S_FFH);

    const size_t out_bytes = (size_t)out_size * 4;
    char* tail = (char*)d_out + ((out_bytes - tail_bytes) & ~(size_t)255);

    float* xA   = (float*)tail;
    float* xB   = xA + F_XA;
    float* qkvb = xB + F_XA;                                     // [1024,2304] f32
    float* bufS = qkvb + F_QKV;                                  // 4 split-K slabs [1024,768] f32
    unsigned short* bw_ip = (unsigned short*)(bufS + F_SLAB);
    unsigned short* bw_ow = bw_ip + N_IP;
    unsigned short* bw_l1 = bw_ow + N_OW;
    unsigned short* bw_l2 = bw_l1 + N_L1;
    unsigned short* bw_c1 = bw_l2 + N_L2;
    unsigned short* xAb   = bw_c1 + N_C1;
    unsigned short* xBb   = xAb + S_ACT;
    unsigned short* attnb = xBb + S_ACT;                         // attn out bf16
    unsigned short* bufHb = attnb + S_ACT;                       // FF hidden bf16 [1024,3072]

    // fused weight conversion (6 segments incl. cls_w1 zero-pad rows)
    {
        CvtSegs segs{};
        const float* srcs[6] = {ipw, oww, l1w, l2w, cw1, nullptr};
        unsigned short* dsts[6] = {bw_ip, bw_ow, bw_l1, bw_l2, bw_c1, bw_c1 + (size_t)100 * Dc};
        const unsigned int cnt[6] = {(unsigned)(N_IP / 4), (unsigned)(N_OW / 4),
                                     (unsigned)(N_L1 / 4), (unsigned)(N_L2 / 4),
                                     (unsigned)(100 * Dc / 4), (unsigned)(12 * Dc / 4)};
        unsigned int acc = 0;
        for (int i = 0; i < 6; ++i) { segs.src[i] = srcs[i]; segs.dst[i] = dsts[i]; acc += cnt[i]; segs.end[i] = acc; }
        segs.src[6] = nullptr; segs.dst[6] = dsts[5]; segs.end[6] = 0xFFFFFFFFu;
        segs.total = acc;
        cvt_multi_kernel<<<2048, 256, 0, stream>>>(segs);
    }
    cvt_c2_kernel<<<1024, 256, 0, stream>>>(cw2, bw_c2);

    // mention pooling -> xA (f32) + xAb (bf16)
    pool_kernel<<<TOK, 256, 0, stream>>>(lhs, attnw, pos, emask, xA, xAb);

    auto g64 = [&](const unsigned short* A, int lda, const unsigned short* B, int ldb,
                   const float* bias, void* C, int ldc, int N, int K, int relu,
                   int ks, int outbf, bool swz) {
        int gx = (N + 63) / 64, nx = -1;
        if (swz) { nx = gx; gx = (gx + 7) & ~7; }
        dim3 grid(gx, TOK / 64, ks);
        if (outbf) gemm_bf16_kernel<64, 64, 2, 2, 1><<<grid, 256, 0, stream>>>(A, lda, B, ldb, bias, C, ldc, TOK, N, K, relu, nx);
        else       gemm_bf16_kernel<64, 64, 2, 2, 0><<<grid, 256, 0, stream>>>(A, lda, B, ldb, bias, C, ldc, TOK, N, K, relu, nx);
    };

    for (int l = 0; l < Lc; ++l) {
        // QKV: [1024,768] x [2304,768]^T -> f32 qkvb (bias in-GEMM)
        g64(xAb, Dc, bw_ip + (size_t)l * 3 * Dc * Dc, Dc, ipb + (size_t)l * 3 * Dc,
            qkvb, 3 * Dc, 3 * Dc, Dc, 0, 1, 0, false);
        attn_kernel<<<Bc * Hc, 256, 0, stream>>>(qkvb, attnb);
        // out-proj: split-K=4 (K=192 each) -> 4 f32 slabs; bias folded into addln
        g64(attnb, Dc, bw_ow + (size_t)l * Dc * Dc, Dc, nullptr,
            bufS, Dc, Dc, Dc / 4, 0, 4, 0, false);
        addln_kernel<<<TOK, 256, 0, stream>>>(xA, bufS, 4, owb + (size_t)l * Dc,
                                              g1 + (size_t)l * Dc, b1 + (size_t)l * Dc, xB, xBb);
        // FF1: relu + bias in-GEMM, bf16 out (only feeds FF2); XCD swizzle (gx=48 exact)
        g64(xBb, Dc, bw_l1 + (size_t)l * DFFc * Dc, Dc, l1b + (size_t)l * DFFc,
            bufHb, DFFc, DFFc, Dc, 1, 1, 1, true);
        // FF2: split-K=4 (K=768 each) -> 4 f32 slabs; bias folded into addln
        g64(bufHb, DFFc, bw_l2 + (size_t)l * Dc * DFFc, DFFc, nullptr,
            bufS, Dc, Dc, DFFc / 4, 0, 4, 0, false);
        addln_kernel<<<TOK, 256, 0, stream>>>(xB, bufS, 4, l2b + (size_t)l * Dc,
                                              g2 + (size_t)l * Dc, b2 + (size_t)l * Dc, xA, xAb);
    }

    // classifier stage 1: N=112 (12 zero rows in bw_c1 give zero pad cols), bf16 out
    g64(xAb, Dc, bw_c1, Dc, nullptr, bufCb, KC2, KC2, Dc, 0, 1, 1, false);
    // classifier stage 2: [1024,112] x [100000,112]^T -> f32 out; XCD chunk swizzle
    {
        int nx = (Ec + 127) / 128;          // 782 real col tiles
        int gx = (nx + 7) & ~7;             // 784 padded
        dim3 grid(gx, TOK / 128, 1);
        gemm_bf16_kernel<128, 128, 4, 4, 0><<<grid, 256, 0, stream>>>(
            bufCb, KC2, bw_c2, KC2, cb2, out, Ec, TOK, Ec, KC2, 0, nx);
    }
}

// Round 3
// 1000.450 us; speedup vs baseline: 1.5474x; 1.1977x over previous
//
#include <hip/hip_runtime.h>

// Problem constants
constexpr int Bc = 32, Sc = 512, Dc = 768, Mc = 32, Tc = 30;
constexpr int Hc = 12, DFFc = 3072, Lc = 4, Ec = 100000, HDc = 64;
constexpr int TOK = Bc * Mc; // 1024 token rows
constexpr int KC2 = 128;     // padded K for classifier GEMMs (multiple of BK=64)

typedef float floatx4 __attribute__((ext_vector_type(4)));
typedef __bf16 bfrag8 __attribute__((ext_vector_type(8)));
typedef unsigned short usx8 __attribute__((ext_vector_type(8)));
typedef unsigned short usx4 __attribute__((ext_vector_type(4)));

__device__ __forceinline__ unsigned short f32_to_bf16(float f) {
    unsigned int u = __float_as_uint(f);
    unsigned int r = (u + 0x7FFFu + ((u >> 16) & 1u)) >> 16; // RNE
    return (unsigned short)r;
}

// async global->LDS, 16B per lane; lds ptr must be wave-uniform, gsrc is per-lane
__device__ __forceinline__ void gload_lds16(const void* gsrc, void* lds) {
    __builtin_amdgcn_global_load_lds((const unsigned int*)gsrc, (unsigned int*)lds, 16, 0, 0);
}

// ---------------------------------------------------------------- fused weight cvt
// 7 segments max; src==nullptr => zero-fill (used for cls_w1 pad rows)
struct CvtSegs {
    const float* src[7];
    unsigned short* dst[7];
    unsigned int end[7];   // cumulative counts in float4-chunks
    unsigned int total;
};

__global__ __launch_bounds__(256)
void cvt_multi_kernel(CvtSegs a) {
    const unsigned int stride = gridDim.x * 256;
    for (unsigned int i = blockIdx.x * 256 + threadIdx.x; i < a.total; i += stride) {
        int s = 0;
        while (i >= a.end[s]) ++s;
        const unsigned int off = i - (s ? a.end[s - 1] : 0u);
        usx4 o = (usx4)0;
        if (a.src[s]) {
            floatx4 v = *(const floatx4*)(a.src[s] + 4 * (size_t)off);
            #pragma unroll
            for (int j = 0; j < 4; ++j) o[j] = f32_to_bf16(v[j]);
        }
        *(usx4*)(a.dst[s] + 4 * (size_t)off) = o;
    }
}

// cls_w2 [E,100] f32 -> [E,128] bf16 (28 zero pad cols), aligned rows
__global__ __launch_bounds__(256)
void cvt_c2_kernel(const float* __restrict__ src, unsigned short* __restrict__ dst) {
    const int total = Ec * (KC2 / 8);          // 16 chunks of 8 per row
    const int stride = gridDim.x * 256;
    for (int c = blockIdx.x * 256 + threadIdx.x; c < total; c += stride) {
        const int row = c >> 4, j = c & 15;
        const int col0 = j * 8;
        const float* sp = src + (size_t)row * 100 + col0;
        usx8 o = (usx8)0;
        if (col0 + 8 <= 100) {
            floatx4 v0 = *(const floatx4*)(sp);
            floatx4 v1 = *(const floatx4*)(sp + 4);
            #pragma unroll
            for (int jj = 0; jj < 4; ++jj) { o[jj] = f32_to_bf16(v0[jj]); o[4 + jj] = f32_to_bf16(v1[jj]); }
        } else if (col0 < 100) {
            #pragma unroll
            for (int jj = 0; jj < 8; ++jj)
                if (col0 + jj < 100) o[jj] = f32_to_bf16(sp[jj]);
        }
        *(usx8*)(dst + (size_t)row * KC2 + col0) = o;
    }
}

// ---------------------------------------------------------------- mention pool
__global__ __launch_bounds__(256)
void pool_kernel(const float* __restrict__ lhs, const float* __restrict__ attn_w,
                 const int* __restrict__ pos, const int* __restrict__ emask,
                 float* __restrict__ x0, unsigned short* __restrict__ x0b) {
    const int bm = blockIdx.x;          // b*32+m
    const int b = bm >> 5;
    const int tid = threadIdx.x;
    __shared__ float s_logit[32];
    __shared__ float s_w[32];
    __shared__ int s_valid[32];

    if (tid == 0) {
        int em = emask[bm];
        int ok = 1;
        for (int t = 0; t < Tc; ++t) {
            if (pos[bm * Tc + t] == -1) ok = 0;
            s_valid[t] = (ok && em) ? 1 : 0;
        }
    }
    __syncthreads();

    const int wid = tid >> 6, lane = tid & 63;
    for (int t = wid; t < Tc; t += 4) {
        float p = 0.f;
        const float* row = lhs + ((size_t)b * Sc + t) * Dc;
        for (int d = lane; d < Dc; d += 64) p += row[d] * attn_w[d];
        #pragma unroll
        for (int off = 32; off > 0; off >>= 1) p += __shfl_down(p, off);
        if (lane == 0) s_logit[t] = s_valid[t] ? p : 0.0f;  // attn_b cancels in softmax
    }
    __syncthreads();
    if (tid == 0) {
        float mx = -1e30f;
        for (int t = 0; t < Tc; ++t) mx = fmaxf(mx, s_logit[t]);
        float sum = 0.f;
        for (int t = 0; t < Tc; ++t) { float e = expf(s_logit[t] - mx); s_w[t] = e; sum += e; }
        float inv = 1.0f / sum;
        for (int t = 0; t < Tc; ++t) s_w[t] = s_valid[t] ? s_w[t] * inv : 0.0f;
    }
    __syncthreads();
    for (int d = tid; d < Dc; d += 256) {
        float acc = 0.f;
        for (int t = 0; t < Tc; ++t) acc += s_w[t] * lhs[((size_t)b * Sc + t) * Dc + d];
        x0[(size_t)bm * Dc + d] = acc;
        x0b[(size_t)bm * Dc + d] = f32_to_bf16(acc);
    }
}

// ---------------------------------------------------------------- GEMM  C = A @ B^T (+bias) (opt relu)
// A: bf16 [M,lda]; B: bf16 [N,ldb]; C: f32 or bf16 [M,ldc].
// REQUIRES: M % BM == 0, K % 64 == 0, 16B-aligned rows. N may be ragged only in the
// swizzled/guarded col direction (stores guarded; B OOB rows must be in-bounds memory).
// Staging: global_load_lds width-16, linear LDS dest + pre-swizzled global source
// (cb ^ ((row&7)<<4)); ds_read applies the same XOR -> ~conflict-free (T2, rule #21).
// Split-K via blockIdx.z: A,B advance z*K cols; C advances z*M*ldc (partial slabs).
// nxReal>0 enables XCD chunk swizzle (requires gridDim.x % 8 == 0); padded col-tiles exit.
template <int BM, int BN, int WM, int WN, int OUTBF>
__global__ __launch_bounds__(256)
void gemm_bf16_kernel(const unsigned short* __restrict__ A, int lda,
                      const unsigned short* __restrict__ B, int ldb,
                      const float* __restrict__ bias, void* __restrict__ Cv,
                      int ldc, int M, int N, int K, int relu, int nxReal) {
    constexpr int BK = 64;
    __shared__ unsigned short lA[BM * BK];
    __shared__ unsigned short lB[BN * BK];

    int bx, by;
    if (nxReal > 0) {
        // chunked bijection: XCD k (== bid%8 round-robin) owns contiguous col range,
        // iterating all row-tiles of a column consecutively -> B tile stays in that XCD's L2.
        const int gx = gridDim.x, gy = gridDim.y;
        const int lb = blockIdx.y * gx + blockIdx.x;
        const int xcd = lb & 7, p = lb >> 3;
        const int pq = p / gy;
        bx = xcd * (gx >> 3) + pq;
        by = p - pq * gy;
        if (bx >= nxReal) return;   // uniform across block, before any barrier
    } else {
        bx = blockIdx.x; by = blockIdx.y;
    }
    const int z = blockIdx.z;
    A += (size_t)z * K;
    B += (size_t)z * K;

    const int tid = threadIdx.x;
    const int bm0 = by * BM;
    const int bn0 = bx * BN;

    const int wid = tid >> 6;
    const int lane = tid & 63;
    const int quad = lane >> 4;
    const int l16 = lane & 15;
    const int wr = (wid >> 1) * (WM * 16);
    const int wc = (wid & 1) * (WN * 16);

    floatx4 acc[WM][WN] = {};

    for (int k0 = 0; k0 < K; k0 += BK) {
        // stage A: BM rows x 128 B, 1024-B wave chunks; source byte pre-swizzled
        #pragma unroll
        for (int it = 0; it < BM / 32; ++it) {
            const int chunk = wid * (BM / 32) + it;       // wave-uniform
            const int boff = chunk * 1024 + lane * 16;
            const int row = boff >> 7;
            const int cb = (boff & 127) ^ ((row & 7) << 4);
            gload_lds16((const char*)(A + (size_t)(bm0 + row) * lda + k0) + cb,
                        &lA[chunk * 512]);
        }
        // stage B
        #pragma unroll
        for (int it = 0; it < BN / 32; ++it) {
            const int chunk = wid * (BN / 32) + it;
            const int boff = chunk * 1024 + lane * 16;
            const int row = boff >> 7;
            const int cb = (boff & 127) ^ ((row & 7) << 4);
            gload_lds16((const char*)(B + (size_t)(bn0 + row) * ldb + k0) + cb,
                        &lB[chunk * 512]);
        }
        __syncthreads();   // drains vmcnt (gload_lds) + lgkmcnt
        #pragma unroll
        for (int kk = 0; kk < BK; kk += 32) {
            bfrag8 af[WM], bfr[WN];
            #pragma unroll
            for (int i = 0; i < WM; ++i) {
                const int rowA = wr + i * 16 + l16;
                af[i] = *(const bfrag8*)((const char*)lA + rowA * 128 +
                                         ((kk * 2 + quad * 16) ^ ((rowA & 7) << 4)));
            }
            #pragma unroll
            for (int j = 0; j < WN; ++j) {
                const int rowB = wc + j * 16 + l16;
                bfr[j] = *(const bfrag8*)((const char*)lB + rowB * 128 +
                                          ((kk * 2 + quad * 16) ^ ((rowB & 7) << 4)));
            }
            #pragma unroll
            for (int i = 0; i < WM; ++i)
                #pragma unroll
                for (int j = 0; j < WN; ++j)
                    acc[i][j] = __builtin_amdgcn_mfma_f32_16x16x32_bf16(af[i], bfr[j], acc[i][j], 0, 0, 0);
        }
        __syncthreads();
    }

    #pragma unroll
    for (int i = 0; i < WM; ++i) {
        #pragma unroll
        for (int j = 0; j < WN; ++j) {
            const int col = bn0 + wc + j * 16 + l16;
            if (col < N) {
                const int row0 = bm0 + wr + i * 16 + quad * 4;
                const float bv = bias ? bias[col] : 0.0f;
                #pragma unroll
                for (int r = 0; r < 4; ++r) {
                    float v = acc[i][j][r] + bv;
                    if (relu) v = fmaxf(v, 0.0f);
                    const size_t idx = (size_t)z * M * ldc + (size_t)(row0 + r) * ldc + col;
                    if (OUTBF) ((unsigned short*)Cv)[idx] = f32_to_bf16(v);
                    else       ((float*)Cv)[idx] = v;
                }
            }
        }
    }
}

// ---------------------------------------------------------------- attention (one block per (b,h))
__global__ __launch_bounds__(256)
void attn_kernel(const float* __restrict__ qkv, unsigned short* __restrict__ outb) {
    const int bh = blockIdx.x;
    const int b = bh / Hc, h = bh % Hc;
    const int tid = threadIdx.x;
    __shared__ float sQ[32][65];
    __shared__ float sK[32][65];
    __shared__ float sV[32][65];
    __shared__ float sS[32][33];

    const int m = tid >> 3;
    const int c0 = (tid & 7) * 8;
    {
        const size_t rbase = ((size_t)(b * 32 + m)) * (3 * Dc);
        #pragma unroll
        for (int j = 0; j < 8; ++j) {
            sQ[m][c0 + j] = qkv[rbase + h * HDc + c0 + j];
            sK[m][c0 + j] = qkv[rbase + Dc + h * HDc + c0 + j];
            sV[m][c0 + j] = qkv[rbase + 2 * Dc + h * HDc + c0 + j];
        }
    }
    __syncthreads();

    #pragma unroll
    for (int u = 0; u < 4; ++u) {
        const int e = tid * 4 + u;
        const int q = e >> 5, k = e & 31;
        float s = 0.f;
        #pragma unroll
        for (int d = 0; d < HDc; ++d) s += sQ[q][d] * sK[k][d];
        sS[q][k] = s * 0.125f;
    }
    __syncthreads();
    if (tid < 32) {
        float mx = -1e30f;
        for (int k = 0; k < 32; ++k) mx = fmaxf(mx, sS[tid][k]);
        float sum = 0.f;
        for (int k = 0; k < 32; ++k) { float e = expf(sS[tid][k] - mx); sS[tid][k] = e; sum += e; }
        const float inv = 1.0f / sum;
        for (int k = 0; k < 32; ++k) sS[tid][k] *= inv;
    }
    __syncthreads();
    float o[8] = {};
    for (int k = 0; k < 32; ++k) {
        const float p = sS[m][k];
        #pragma unroll
        for (int j = 0; j < 8; ++j) o[j] += p * sV[k][c0 + j];
    }
    usx8 o8;
    #pragma unroll
    for (int j = 0; j < 8; ++j) o8[j] = f32_to_bf16(o[j]);
    *(usx8*)(&outb[((size_t)(b * 32 + m)) * Dc + h * HDc + c0]) = o8;
}

// ---------------------------------------------------------------- residual + split-K sum + bias + layernorm
// out = LN(xa + sum_{s<nslab} xs[s] + badd) ; writes f32 and bf16 copies
__global__ __launch_bounds__(256)
void addln_kernel(const float* __restrict__ xa, const float* __restrict__ xs, int nslab,
                  const float* __restrict__ badd, const float* __restrict__ g,
                  const float* __restrict__ be, float* __restrict__ outf,
                  unsigned short* __restrict__ outb) {
    const int row = blockIdx.x;
    const int tid = threadIdx.x;
    __shared__ float red[8];
    float v[3];
    float s = 0.f, sq = 0.f;
    #pragma unroll
    for (int i = 0; i < 3; ++i) {
        const int d = tid + i * 256;
        float x = xa[(size_t)row * Dc + d] + badd[d];
        for (int sl = 0; sl < nslab; ++sl)
            x += xs[((size_t)sl * TOK + row) * Dc + d];
        v[i] = x; s += x; sq += x * x;
    }
    #pragma unroll
    for (int off = 32; off > 0; off >>= 1) {
        s += __shfl_down(s, off);
        sq += __shfl_down(sq, off);
    }
    if ((tid & 63) == 0) { red[tid >> 6] = s; red[4 + (tid >> 6)] = sq; }
    __syncthreads();
    const float ts = red[0] + red[1] + red[2] + red[3];
    const float tq = red[4] + red[5] + red[6] + red[7];
    const float mean = ts * (1.0f / Dc);
    const float var = tq * (1.0f / Dc) - mean * mean;
    const float inv = rsqrtf(var + 1e-5f);
    #pragma unroll
    for (int i = 0; i < 3; ++i) {
        const int d = tid + i * 256;
        const float y = (v[i] - mean) * inv * g[d] + be[d];
        outf[(size_t)row * Dc + d] = y;
        outb[(size_t)row * Dc + d] = f32_to_bf16(y);
    }
}

// ---------------------------------------------------------------- launch
extern "C" void kernel_launch(void* const* d_in, const int* in_sizes, int n_in,
                              void* d_out, int out_size, void* d_ws, size_t ws_size,
                              hipStream_t stream) {
    const float* lhs   = (const float*)d_in[0];
    const float* attnw = (const float*)d_in[1];
    // d_in[2] attn_b: scalar, cancels in softmax
    const float* ipw = (const float*)d_in[3];
    const float* ipb = (const float*)d_in[4];
    const float* oww = (const float*)d_in[5];
    const float* owb = (const float*)d_in[6];
    const float* g1  = (const float*)d_in[7];
    const float* b1  = (const float*)d_in[8];
    const float* l1w = (const float*)d_in[9];
    const float* l1b = (const float*)d_in[10];
    const float* l2w = (const float*)d_in[11];
    const float* l2b = (const float*)d_in[12];
    const float* g2  = (const float*)d_in[13];
    const float* b2  = (const float*)d_in[14];
    const float* cw1 = (const float*)d_in[15];
    const float* cw2 = (const float*)d_in[16];
    const float* cb2 = (const float*)d_in[17];
    const int* pos   = (const int*)d_in[18];
    const int* emask = (const int*)d_in[19];
    float* out = (float*)d_out;

    constexpr size_t N_IP = (size_t)Lc * 3 * Dc * Dc;   // 7,077,888
    constexpr size_t N_OW = (size_t)Lc * Dc * Dc;       // 2,359,296
    constexpr size_t N_L1 = (size_t)Lc * DFFc * Dc;     // 9,437,184
    constexpr size_t N_L2 = (size_t)Lc * Dc * DFFc;     // 9,437,184
    constexpr size_t N_C1 = (size_t)KC2 * Dc;           // 98,304 (128 rows, 28 zero)

    // ---- memory map ----
    // d_ws: bw_c2 [E,128] bf16 (25.6 MB) + bufCb [1024,128] bf16 (0.26 MB).
    //       (final-GEMM B staging may over-read <25 KB past bw_c2 -> lands in bufCb, safe)
    // d_out TAIL (~96 MB of 409.6 MB; dead before final GEMM overwrites all of d_out):
    //       f32 activations, then bf16 weights + bf16 activations.
    char* ws = (char*)d_ws;
    unsigned short* bw_c2 = (unsigned short*)ws;                 // [E,128] bf16
    unsigned short* bufCb = bw_c2 + (size_t)Ec * KC2;            // [1024,128] bf16

    constexpr size_t F_XA   = (size_t)TOK * Dc;          // 786,432
    constexpr size_t F_QKV  = (size_t)TOK * 3 * Dc;      // 2,359,296
    constexpr size_t F_SLAB = (size_t)4 * TOK * Dc;      // 3,145,728
    constexpr size_t S_ACT  = (size_t)TOK * Dc;          // bf16 activation count
    constexpr size_t S_FFH  = (size_t)TOK * DFFc;
    constexpr size_t tail_bytes =
        4 * (F_XA + F_XA + F_QKV + F_SLAB) +
        2 * (N_IP + N_OW + N_L1 + N_L2 + N_C1 + 3 * S_ACT + S_FFH);

    const size_t out_bytes = (size_t)out_size * 4;
    char* tail = (char*)d_out + ((out_bytes - tail_bytes) & ~(size_t)255);

    float* xA   = (float*)tail;
    float* xB   = xA + F_XA;
    float* qkvb = xB + F_XA;                                     // [1024,2304] f32
    float* bufS = qkvb + F_QKV;                                  // 4 split-K slabs [1024,768] f32
    unsigned short* bw_ip = (unsigned short*)(bufS + F_SLAB);
    unsigned short* bw_ow = bw_ip + N_IP;
    unsigned short* bw_l1 = bw_ow + N_OW;
    unsigned short* bw_l2 = bw_l1 + N_L1;
    unsigned short* bw_c1 = bw_l2 + N_L2;
    unsigned short* xAb   = bw_c1 + N_C1;
    unsigned short* xBb   = xAb + S_ACT;
    unsigned short* attnb = xBb + S_ACT;                         // attn out bf16
    unsigned short* bufHb = attnb + S_ACT;                       // FF hidden bf16 [1024,3072]

    // fused weight conversion (6 segments incl. cls_w1 zero-pad rows)
    {
        CvtSegs segs{};
        const float* srcs[6] = {ipw, oww, l1w, l2w, cw1, nullptr};
        unsigned short* dsts[6] = {bw_ip, bw_ow, bw_l1, bw_l2, bw_c1, bw_c1 + (size_t)100 * Dc};
        const unsigned int cnt[6] = {(unsigned)(N_IP / 4), (unsigned)(N_OW / 4),
                                     (unsigned)(N_L1 / 4), (unsigned)(N_L2 / 4),
                                     (unsigned)(100 * Dc / 4), (unsigned)(28 * Dc / 4)};
        unsigned int acc = 0;
        for (int i = 0; i < 6; ++i) { segs.src[i] = srcs[i]; segs.dst[i] = dsts[i]; acc += cnt[i]; segs.end[i] = acc; }
        segs.src[6] = nullptr; segs.dst[6] = dsts[5]; segs.end[6] = 0xFFFFFFFFu;
        segs.total = acc;
        cvt_multi_kernel<<<2048, 256, 0, stream>>>(segs);
    }
    cvt_c2_kernel<<<1024, 256, 0, stream>>>(cw2, bw_c2);

    // mention pooling -> xA (f32) + xAb (bf16)
    pool_kernel<<<TOK, 256, 0, stream>>>(lhs, attnw, pos, emask, xA, xAb);

    auto g64 = [&](const unsigned short* A, int lda, const unsigned short* B, int ldb,
                   const float* bias, void* C, int ldc, int N, int K, int relu,
                   int ks, int outbf, bool swz) {
        int gx = (N + 63) / 64, nx = -1;
        if (swz) { nx = gx; gx = (gx + 7) & ~7; }
        dim3 grid(gx, TOK / 64, ks);
        if (outbf) gemm_bf16_kernel<64, 64, 2, 2, 1><<<grid, 256, 0, stream>>>(A, lda, B, ldb, bias, C, ldc, TOK, N, K, relu, nx);
        else       gemm_bf16_kernel<64, 64, 2, 2, 0><<<grid, 256, 0, stream>>>(A, lda, B, ldb, bias, C, ldc, TOK, N, K, relu, nx);
    };

    for (int l = 0; l < Lc; ++l) {
        // QKV: [1024,768] x [2304,768]^T -> f32 qkvb (bias in-GEMM)
        g64(xAb, Dc, bw_ip + (size_t)l * 3 * Dc * Dc, Dc, ipb + (size_t)l * 3 * Dc,
            qkvb, 3 * Dc, 3 * Dc, Dc, 0, 1, 0, false);
        attn_kernel<<<Bc * Hc, 256, 0, stream>>>(qkvb, attnb);
        // out-proj: split-K=4 (K=192 each) -> 4 f32 slabs; bias folded into addln
        g64(attnb, Dc, bw_ow + (size_t)l * Dc * Dc, Dc, nullptr,
            bufS, Dc, Dc, Dc / 4, 0, 4, 0, false);
        addln_kernel<<<TOK, 256, 0, stream>>>(xA, bufS, 4, owb + (size_t)l * Dc,
                                              g1 + (size_t)l * Dc, b1 + (size_t)l * Dc, xB, xBb);
        // FF1: relu + bias in-GEMM, bf16 out (only feeds FF2); XCD swizzle (gx=48 exact)
        g64(xBb, Dc, bw_l1 + (size_t)l * DFFc * Dc, Dc, l1b + (size_t)l * DFFc,
            bufHb, DFFc, DFFc, Dc, 1, 1, 1, true);
        // FF2: split-K=4 (K=768 each) -> 4 f32 slabs; bias folded into addln
        g64(bufHb, DFFc, bw_l2 + (size_t)l * Dc * DFFc, DFFc, nullptr,
            bufS, Dc, Dc, DFFc / 4, 0, 4, 0, false);
        addln_kernel<<<TOK, 256, 0, stream>>>(xB, bufS, 4, l2b + (size_t)l * Dc,
                                              g2 + (size_t)l * Dc, b2 + (size_t)l * Dc, xA, xAb);
    }

    // classifier stage 1: N=128 (28 zero rows in bw_c1 -> zero pad cols), bf16 out
    g64(xAb, Dc, bw_c1, Dc, nullptr, bufCb, KC2, KC2, Dc, 0, 1, 1, false);
    // classifier stage 2: [1024,128] x [100000,128]^T -> f32 out; XCD chunk swizzle
    {
        int nx = (Ec + 127) / 128;          // 782 real col tiles
        int gx = (nx + 7) & ~7;             // 784 padded
        dim3 grid(gx, TOK / 128, 1);
        gemm_bf16_kernel<128, 128, 4, 4, 0><<<grid, 256, 0, stream>>>(
            bufCb, KC2, bw_c2, KC2, cb2, out, Ec, TOK, Ec, KC2, 0, nx);
    }
}